// Round 2
// baseline (1892.450 us; speedup 1.0000x reference)
//
#include <hip/hip_runtime.h>
#include <cstdint>

#define NNODES 200000
#define NCH 128
#define CGC 64
#define NBATCH 4
#define DHW 262144      // 64*64*64
#define K1 192
#define HID 128

#define VOL_BYTES   268435456ull                 // 4*DHW*64*4
#define PART_OFF    268435456ull
#define PART_BYTES  8388608ull                   // 16384 waves * 128 f32
#define STAT_OFF    (PART_OFF + PART_BYTES)
#define PK_OFF      (STAT_OFF + 2048ull)

__device__ __forceinline__ uint32_t f2bf(float f){
  uint32_t x = __float_as_uint(f);
  return (x + 0x7fffu + ((x >> 16) & 1u)) >> 16;   // RNE to bf16
}
__device__ __forceinline__ float bflo(uint32_t w){ return __uint_as_float(w << 16); }
__device__ __forceinline__ float bfhi(uint32_t w){ return __uint_as_float(w & 0xffff0000u); }
__device__ __forceinline__ float siluf(float a){ return a / (1.f + __expf(-a)); }

// ---------------- pack MLP weights to bf16 pairs ----------------
// w1p[i][j]   (i<192, j<64): (w1[j][i], w1[j+64][i])
// w2p[i][j]   (i<128, j<64): (w2[j][i], w2[j+64][i])
// wnp[i2][o]  (i2<64, o<64): (wn2g[o][2*i2], wn2g[o][2*i2+1])
__global__ void pack_weights(const float* __restrict__ w1, const float* __restrict__ w2,
                             const float* __restrict__ wn2g, uint32_t* __restrict__ pk)
{
  int t = blockIdx.x * 256 + threadIdx.x;
  if (t < K1 * 64) {
    int i = t >> 6, j = t & 63;
    pk[t] = f2bf(w1[j * K1 + i]) | (f2bf(w1[(j + 64) * K1 + i]) << 16);
  } else if (t < K1 * 64 + HID * 64) {
    int u = t - K1 * 64; int i = u >> 6, j = u & 63;
    pk[t] = f2bf(w2[j * HID + i]) | (f2bf(w2[(j + 64) * HID + i]) << 16);
  } else if (t < K1 * 64 + HID * 64 + 64 * 64) {
    int u = t - (K1 * 64 + HID * 64); int i2 = u >> 6, o = u & 63;
    pk[t] = f2bf(wn2g[o * NCH + 2 * i2]) | (f2bf(wn2g[o * NCH + 2 * i2 + 1]) << 16);
  }
}

// ---------------- per-node fused kernel ----------------
// 1 wave per node (grid-stride). lane = channel (0..63); lane l owns ch l and l+64.
__launch_bounds__(1024, 1)
__global__ void node_kernel(const float* __restrict__ h, const float* __restrict__ x,
                            const float* __restrict__ grid, const int* __restrict__ nbat,
                            const float* __restrict__ cmin, const float* __restrict__ sstr,
                            const uint32_t* __restrict__ pk,
                            const float* __restrict__ b1, const float* __restrict__ b2,
                            const float* __restrict__ ln_g, const float* __restrict__ ln_b,
                            const float* __restrict__ bn2g,
                            float* __restrict__ hn_out, float* __restrict__ vol)
{
  __shared__ uint32_t w1p[K1 * 64];     // 49152 B
  __shared__ uint32_t w2p[HID * 64];    // 32768 B
  __shared__ uint32_t wnp[64 * 64];     // 16384 B
  __shared__ float    zbuf[16][K1];     // 12288 B  (per-wave z / act / hn scratch)

  for (int t = threadIdx.x; t < (K1 + HID + 64) * 64; t += 1024) {
    uint32_t v = pk[t];
    if (t < K1 * 64)            w1p[t] = v;
    else if (t < (K1 + HID) * 64) w2p[t - K1 * 64] = v;
    else                        wnp[t - (K1 + HID) * 64] = v;
  }
  __syncthreads();

  const int l  = threadIdx.x & 63;
  const int w  = threadIdx.x >> 6;
  const int gw = blockIdx.x * 16 + w;
  const int nw = gridDim.x * 16;
  float* zw = zbuf[w];

  const float c0 = cmin[0], c1 = cmin[1], c2 = cmin[2];
  const float st0 = sstr[0], st1 = sstr[1], st2 = sstr[2];
  const float bia0 = b1[l],  bia1 = b1[64 + l];
  const float bib0 = b2[l],  bib1 = b2[64 + l];
  const float lg0 = ln_g[l], lg1 = ln_g[64 + l];
  const float lb0 = ln_b[l], lb1 = ln_b[64 + l];
  const float bnp = bn2g[l];

  for (int n = gw; n < NNODES; n += nw) {
    // ---- corner data (uniform across lanes) ----
    float gx = (x[n * 3 + 0] - c0) / st0;
    float gy = (x[n * 3 + 1] - c1) / st1;
    float gz = (x[n * 3 + 2] - c2) / st2;
    float fx0 = floorf(gx), fy0 = floorf(gy), fz0 = floorf(gz);
    float fx = fminf(fmaxf(gx - fx0, 0.f), 1.f);
    float fy = fminf(fmaxf(gy - fy0, 0.f), 1.f);
    float fz = fminf(fmaxf(gz - fz0, 0.f), 1.f);
    int ix0 = (int)fx0, iy0 = (int)fy0, iz0 = (int)fz0;
    int b = nbat[n];

    float cw[8]; int cf[8];
    #pragma unroll
    for (int k = 0; k < 8; ++k) {
      int xi = (k & 1) ? ix0 + 1 : ix0;
      int yi = (k & 2) ? iy0 + 1 : iy0;
      int zi = (k & 4) ? iz0 + 1 : iz0;
      float wx = (k & 1) ? fx : 1.f - fx;
      float wy = (k & 2) ? fy : 1.f - fy;
      float wz = (k & 4) ? fz : 1.f - fz;
      bool valid = (xi >= 0) & (xi < 64) & (yi >= 0) & (yi < 64) & (zi >= 0) & (zi < 64);
      int xc = min(max(xi, 0), 63), yc = min(max(yi, 0), 63), zc = min(max(zi, 0), 63);
      cw[k] = valid ? wx * wy * wz : 0.f;
      cf[k] = (zc << 12) | (yc << 6) | xc;
    }

    // ---- gather: sampled[l] ----
    const float* gb = grid + ((size_t)(b * CGC + l)) * DHW;
    float samp = 0.f;
    #pragma unroll
    for (int k = 0; k < 8; ++k) samp = fmaf(cw[k], gb[cf[k]], samp);

    float hA = h[(size_t)n * NCH + l];
    float hB = h[(size_t)n * NCH + 64 + l];
    zw[l] = hA; zw[64 + l] = hB; zw[128 + l] = samp;
    asm volatile("s_waitcnt lgkmcnt(0)" ::: "memory");

    // ---- layer1: 192 -> 128, silu ----
    float a0 = bia0, a1 = bia1;
    #pragma unroll
    for (int i4 = 0; i4 < K1 / 4; ++i4) {
      float4 z4 = *(const float4*)&zw[i4 * 4];
      uint32_t wv;
      wv = w1p[(i4 * 4 + 0) * 64 + l]; a0 = fmaf(z4.x, bflo(wv), a0); a1 = fmaf(z4.x, bfhi(wv), a1);
      wv = w1p[(i4 * 4 + 1) * 64 + l]; a0 = fmaf(z4.y, bflo(wv), a0); a1 = fmaf(z4.y, bfhi(wv), a1);
      wv = w1p[(i4 * 4 + 2) * 64 + l]; a0 = fmaf(z4.z, bflo(wv), a0); a1 = fmaf(z4.z, bfhi(wv), a1);
      wv = w1p[(i4 * 4 + 3) * 64 + l]; a0 = fmaf(z4.w, bflo(wv), a0); a1 = fmaf(z4.w, bfhi(wv), a1);
    }
    float s0 = siluf(a0), s1 = siluf(a1);
    zw[l] = s0; zw[64 + l] = s1;
    asm volatile("s_waitcnt lgkmcnt(0)" ::: "memory");

    // ---- layer2: 128 -> 128 ----
    float m0 = bib0, m1 = bib1;
    #pragma unroll
    for (int i4 = 0; i4 < HID / 4; ++i4) {
      float4 z4 = *(const float4*)&zw[i4 * 4];
      uint32_t wv;
      wv = w2p[(i4 * 4 + 0) * 64 + l]; m0 = fmaf(z4.x, bflo(wv), m0); m1 = fmaf(z4.x, bfhi(wv), m1);
      wv = w2p[(i4 * 4 + 1) * 64 + l]; m0 = fmaf(z4.y, bflo(wv), m0); m1 = fmaf(z4.y, bfhi(wv), m1);
      wv = w2p[(i4 * 4 + 2) * 64 + l]; m0 = fmaf(z4.z, bflo(wv), m0); m1 = fmaf(z4.z, bfhi(wv), m1);
      wv = w2p[(i4 * 4 + 3) * 64 + l]; m0 = fmaf(z4.w, bflo(wv), m0); m1 = fmaf(z4.w, bfhi(wv), m1);
    }

    // ---- residual + LayerNorm ----
    float hn0 = hA + m0, hn1 = hB + m1;
    float ss = hn0 + hn1, qq = hn0 * hn0 + hn1 * hn1;
    #pragma unroll
    for (int off = 32; off >= 1; off >>= 1) {
      ss += __shfl_xor(ss, off, 64);
      qq += __shfl_xor(qq, off, 64);
    }
    float mu = ss * (1.f / 128.f);
    float var = qq * (1.f / 128.f) - mu * mu;
    float rstd = rsqrtf(var + 1e-5f);
    float yA = (hn0 - mu) * rstd * lg0 + lb0;
    float yB = (hn1 - mu) * rstd * lg1 + lb1;
    hn_out[(size_t)n * NCH + l] = yA;
    hn_out[(size_t)n * NCH + 64 + l] = yB;
    zw[l] = yA; zw[64 + l] = yB;
    asm volatile("s_waitcnt lgkmcnt(0)" ::: "memory");

    // ---- proj: 128 -> 64 ----
    float pr = bnp;
    #pragma unroll
    for (int p = 0; p < 32; ++p) {
      float4 hv = *(const float4*)&zw[p * 4];
      uint32_t wa = wnp[(2 * p) * 64 + l];
      uint32_t wb = wnp[(2 * p + 1) * 64 + l];
      pr = fmaf(hv.x, bflo(wa), pr);
      pr = fmaf(hv.y, bfhi(wa), pr);
      pr = fmaf(hv.z, bflo(wb), pr);
      pr = fmaf(hv.w, bfhi(wb), pr);
    }

    // ---- scatter-add to vol (channel-last) ----
    size_t vb = (size_t)b * DHW;
    #pragma unroll
    for (int k = 0; k < 8; ++k) {
      if (cw[k] != 0.f)
        atomicAdd(&vol[(vb + (size_t)cf[k]) * 64 + l], cw[k] * pr);
    }
  }
}

// ---------------- per-voxel MLP kernel ----------------
// one thread per voxel; accumulators statically indexed only.
__global__ void voxel_kernel(const float* __restrict__ grid, const float* __restrict__ vol,
                             const float* __restrict__ wc1, const float* __restrict__ bc1,
                             const float* __restrict__ wc2, const float* __restrict__ bc2,
                             float* __restrict__ gr_out, float* __restrict__ partials)
{
  __shared__ float w1t[128 * 64];   // [c][o] transposed wc1
  __shared__ float w2s[64 * 64];    // [o][j] original wc2
  __shared__ float b1s[64], b2s[64];

  for (int t = threadIdx.x; t < 8192; t += 256) {
    int o = t >> 7, c = t & 127;
    w1t[c * 64 + o] = wc1[t];
  }
  for (int t = threadIdx.x; t < 4096; t += 256) w2s[t] = wc2[t];
  if (threadIdx.x < 64) { b1s[threadIdx.x] = bc1[threadIdx.x]; b2s[threadIdx.x] = bc2[threadIdx.x]; }
  __syncthreads();

  const int v = blockIdx.x * 256 + threadIdx.x;   // 0 .. 1048575
  const int b = v >> 18;
  const int dhw = v & (DHW - 1);
  const float* gvox = grid + (size_t)(b * 64) * DHW + dhw;

  float acc[64];
  #pragma unroll
  for (int o = 0; o < 64; ++o) acc[o] = b1s[o];

  // grid half of cat
  #pragma unroll 4
  for (int c = 0; c < 64; ++c) {
    float gc = gvox[(size_t)c * DHW];
    const float4* wr = (const float4*)&w1t[c * 64];
    #pragma unroll
    for (int o4 = 0; o4 < 16; ++o4) {
      float4 w4 = wr[o4];
      acc[o4 * 4 + 0] = fmaf(gc, w4.x, acc[o4 * 4 + 0]);
      acc[o4 * 4 + 1] = fmaf(gc, w4.y, acc[o4 * 4 + 1]);
      acc[o4 * 4 + 2] = fmaf(gc, w4.z, acc[o4 * 4 + 2]);
      acc[o4 * 4 + 3] = fmaf(gc, w4.w, acc[o4 * 4 + 3]);
    }
  }
  // splat half of cat
  const float4* vv4 = (const float4*)(vol + (size_t)v * 64);
  #pragma unroll 2
  for (int c4 = 0; c4 < 16; ++c4) {
    float4 vv = vv4[c4];
    const float* vc = (const float*)&vv;
    #pragma unroll
    for (int j = 0; j < 4; ++j) {
      float vcj = vc[j];
      const float4* wr = (const float4*)&w1t[(64 + c4 * 4 + j) * 64];
      #pragma unroll
      for (int o4 = 0; o4 < 16; ++o4) {
        float4 w4 = wr[o4];
        acc[o4 * 4 + 0] = fmaf(vcj, w4.x, acc[o4 * 4 + 0]);
        acc[o4 * 4 + 1] = fmaf(vcj, w4.y, acc[o4 * 4 + 1]);
        acc[o4 * 4 + 2] = fmaf(vcj, w4.z, acc[o4 * 4 + 2]);
        acc[o4 * 4 + 3] = fmaf(vcj, w4.w, acc[o4 * 4 + 3]);
      }
    }
  }
  // silu -> g1 (in place)
  #pragma unroll
  for (int o = 0; o < 64; ++o) acc[o] = siluf(acc[o]);

  // layer2 + residual + store + per-wave stats, per output channel
  float* pbase = partials + (size_t)(v >> 6) * 128;
  for (int o = 0; o < 64; ++o) {
    float a2 = b2s[o];
    const float4* wr = (const float4*)&w2s[o * 64];
    #pragma unroll
    for (int j4 = 0; j4 < 16; ++j4) {
      float4 w4 = wr[j4];
      a2 = fmaf(acc[j4 * 4 + 0], w4.x, a2);
      a2 = fmaf(acc[j4 * 4 + 1], w4.y, a2);
      a2 = fmaf(acc[j4 * 4 + 2], w4.z, a2);
      a2 = fmaf(acc[j4 * 4 + 3], w4.w, a2);
    }
    float gc = gvox[(size_t)o * DHW];
    float grv = gc + a2;
    gr_out[(size_t)(b * 64 + o) * DHW + dhw] = grv;
    float sv = grv, qv = grv * grv;
    #pragma unroll
    for (int off = 32; off >= 1; off >>= 1) {
      sv += __shfl_xor(sv, off, 64);
      qv += __shfl_xor(qv, off, 64);
    }
    if ((threadIdx.x & 63) == 0) { pbase[2 * o] = sv; pbase[2 * o + 1] = qv; }
  }
}

// ---------------- reduce partials -> per (b,c) scale/shift ----------------
__global__ void stats_kernel(const float* __restrict__ partials, const float* __restrict__ in_g,
                             const float* __restrict__ in_b, float* __restrict__ stats)
{
  int bo = blockIdx.x;            // b*64 + o
  int b = bo >> 6, o = bo & 63;
  float s = 0.f, q = 0.f;
  for (int k = threadIdx.x; k < 4096; k += 256) {
    const float* p = partials + (size_t)(b * 4096 + k) * 128 + 2 * o;
    s += p[0]; q += p[1];
  }
  __shared__ float sred[256], qred[256];
  sred[threadIdx.x] = s; qred[threadIdx.x] = q;
  __syncthreads();
  for (int st = 128; st >= 1; st >>= 1) {
    if (threadIdx.x < st) { sred[threadIdx.x] += sred[threadIdx.x + st]; qred[threadIdx.x] += qred[threadIdx.x + st]; }
    __syncthreads();
  }
  if (threadIdx.x == 0) {
    float mu = sred[0] * (1.f / (float)DHW);
    float var = qred[0] * (1.f / (float)DHW) - mu * mu;
    float rstd = rsqrtf(var + 1e-5f);
    float scale = rstd * in_g[o];
    stats[2 * bo] = scale;
    stats[2 * bo + 1] = in_b[o] - mu * scale;
  }
}

// ---------------- apply instance norm in place ----------------
__global__ void norm_kernel(float* __restrict__ gr, const float* __restrict__ stats)
{
  const size_t total4 = (size_t)NBATCH * 64 * DHW / 4;   // 16777216 float4
  size_t stride = (size_t)gridDim.x * 256;
  for (size_t i = blockIdx.x * 256 + threadIdx.x; i < total4; i += stride) {
    int bo = (int)(i >> 16);                              // 65536 float4 per (b,c)
    float scale = stats[2 * bo], shift = stats[2 * bo + 1];
    float4 v = ((float4*)gr)[i];
    v.x = fmaf(v.x, scale, shift);
    v.y = fmaf(v.y, scale, shift);
    v.z = fmaf(v.z, scale, shift);
    v.w = fmaf(v.w, scale, shift);
    ((float4*)gr)[i] = v;
  }
}

extern "C" void kernel_launch(void* const* d_in, const int* in_sizes, int n_in,
                              void* d_out, int out_size, void* d_ws, size_t ws_size,
                              hipStream_t stream)
{
  const float* h     = (const float*)d_in[0];
  const float* x     = (const float*)d_in[1];
  const float* grid  = (const float*)d_in[2];
  const int*   nbat  = (const int*)d_in[3];
  const float* cmin  = (const float*)d_in[4];
  const float* sstr  = (const float*)d_in[5];
  const float* w1    = (const float*)d_in[6];
  const float* b1    = (const float*)d_in[7];
  const float* w2    = (const float*)d_in[8];
  const float* b2    = (const float*)d_in[9];
  const float* ln_g  = (const float*)d_in[10];
  const float* ln_b  = (const float*)d_in[11];
  const float* wn2g  = (const float*)d_in[12];
  const float* bn2g  = (const float*)d_in[13];
  const float* wc1   = (const float*)d_in[14];
  const float* bc1   = (const float*)d_in[15];
  const float* wc2   = (const float*)d_in[16];
  const float* bc2   = (const float*)d_in[17];
  const float* in_g  = (const float*)d_in[18];
  const float* in_b  = (const float*)d_in[19];

  float* hn_out = (float*)d_out;
  float* gr_out = (float*)d_out + (size_t)NNODES * NCH;

  char* ws = (char*)d_ws;
  float*    vol      = (float*)ws;                     // 268 MB, zeroed each call
  float*    partials = (float*)(ws + PART_OFF);        // 8 MB
  float*    stats    = (float*)(ws + STAT_OFF);        // 2 KB
  uint32_t* pk       = (uint32_t*)(ws + PK_OFF);       // 96 KB

  (void)hipMemsetAsync(vol, 0, VOL_BYTES, stream);
  pack_weights<<<96, 256, 0, stream>>>(w1, w2, wn2g, pk);
  node_kernel<<<256, 1024, 0, stream>>>(h, x, grid, nbat, cmin, sstr, pk,
                                        b1, b2, ln_g, ln_b, bn2g, hn_out, vol);
  voxel_kernel<<<4096, 256, 0, stream>>>(grid, vol, wc1, bc1, wc2, bc2, gr_out, partials);
  stats_kernel<<<256, 256, 0, stream>>>(partials, in_g, in_b, stats);
  norm_kernel<<<4096, 256, 0, stream>>>(gr_out, stats);
}

// Round 4
// 1330.825 us; speedup vs baseline: 1.4220x; 1.4220x over previous
//
#include <hip/hip_runtime.h>
#include <cstdint>

#define NNODES 200000
#define NCH 128
#define CGC 64
#define NBATCH 4
#define DHW 262144      // 64*64*64
#define K1 192
#define HID 128

#define VOL_BYTES   268435456ull                 // 4*DHW*64*4
#define PART_OFF    268435456ull
#define PART_BYTES  8388608ull                   // 16384 waves * 128 f32
#define STAT_OFF    (PART_OFF + PART_BYTES)
#define PK_OFF      (STAT_OFF + 2048ull)
#define PK_BYTES    98304ull                     // 24576 u32
#define GT_OFF      (PK_OFF + PK_BYTES)
#define GT_BYTES    134217728ull                 // 4*DHW*32*4  (fp16 pairs)

typedef _Float16 h2 __attribute__((ext_vector_type(2)));
typedef __fp16  fp16x2 __attribute__((ext_vector_type(2)));

__device__ __forceinline__ uint32_t pack_h2(float a, float b){
  fp16x2 p = __builtin_amdgcn_cvt_pkrtz(a, b);
  return __builtin_bit_cast(uint32_t, p);
}
__device__ __forceinline__ h2 as_h2(uint32_t w){ return __builtin_bit_cast(h2, w); }
__device__ __forceinline__ float dot2(uint32_t zp, uint32_t wp, float acc){
  return __builtin_amdgcn_fdot2(as_h2(zp), as_h2(wp), acc, false);
}
__device__ __forceinline__ float siluf(float a){ return a / (1.f + __expf(-a)); }

// ---------------- pack MLP weights to fp16 pairs ----------------
// Layout (u32 units):
//  w1x [0,12288):   ((m2*64 + l)*4 + q), m=2*m2+(q>>1), j=(q&1)?64+l:l
//                   pair inputs: m<64 -> (m, 64+m) ; m>=64 -> (128+2*(m-64), 129+2*(m-64))
//  w2x [12288,20480): same scheme, K=128, pair m -> (m, 64+m)
//  wnx [20480,24576): ((m2*64 + o)*4 + q), pair m=4*m2+q -> (m, 64+m), output o
__global__ void pack_weights(const float* __restrict__ w1, const float* __restrict__ w2,
                             const float* __restrict__ wn2g, uint32_t* __restrict__ pk)
{
  int t = blockIdx.x * 256 + threadIdx.x;
  if (t < 12288) {
    int q = t & 3, l = (t >> 2) & 63, m2 = t >> 8;
    int m = 2 * m2 + (q >> 1);
    int j = (q & 1) ? 64 + l : l;
    int i0 = (m < 64) ? m : 128 + 2 * (m - 64);
    int i1 = (m < 64) ? 64 + m : 128 + 2 * (m - 64) + 1;
    pk[t] = pack_h2(w1[j * K1 + i0], w1[j * K1 + i1]);
  } else if (t < 20480) {
    int u = t - 12288;
    int q = u & 3, l = (u >> 2) & 63, m2 = u >> 8;
    int m = 2 * m2 + (q >> 1);
    int j = (q & 1) ? 64 + l : l;
    pk[t] = pack_h2(w2[j * HID + m], w2[j * HID + 64 + m]);
  } else if (t < 24576) {
    int u = t - 20480;
    int q = u & 3, o = (u >> 2) & 63, m2 = u >> 8;
    int m = 4 * m2 + q;
    pk[t] = pack_h2(wn2g[o * HID + m], wn2g[o * HID + 64 + m]);
  }
}

// ---------------- transpose grid -> channel-last fp16 pairs ----------------
// gridT[b][dhw][p] (p<32) = (fp16(grid[b][2p][dhw]), fp16(grid[b][2p+1][dhw]))
__global__ void transpose_kernel(const float* __restrict__ grid, uint32_t* __restrict__ gt)
{
  __shared__ float tile[64][65];
  int bx = blockIdx.x;                  // 0..16383
  int b = bx >> 12;
  int dhw0 = (bx & 4095) << 6;
  const float* gbase = grid + ((size_t)b * 64) * DHW + dhw0;
  int c0 = threadIdx.x >> 6, d = threadIdx.x & 63;
  #pragma unroll
  for (int i = 0; i < 16; ++i)
    tile[i * 4 + c0][d] = gbase[(size_t)(i * 4 + c0) * DHW + d];
  __syncthreads();
  uint32_t* tb = gt + ((size_t)b * DHW + dhw0) * 32;
  int p = threadIdx.x & 31, r0 = threadIdx.x >> 5;   // r0 0..7
  #pragma unroll
  for (int i = 0; i < 8; ++i) {
    int dd = i * 8 + r0;
    tb[(size_t)dd * 32 + p] = pack_h2(tile[2 * p][dd], tile[2 * p + 1][dd]);
  }
}

// ---------------- per-node fused kernel ----------------
// 1 wave per 2 nodes. lane l owns output channels (l, l+64).
__launch_bounds__(1024)
__global__ void node_kernel(const float* __restrict__ h, const float* __restrict__ x,
                            const uint32_t* __restrict__ gridT, const int* __restrict__ nbat,
                            const float* __restrict__ cmin, const float* __restrict__ sstr,
                            const uint32_t* __restrict__ pk,
                            const float* __restrict__ b1, const float* __restrict__ b2,
                            const float* __restrict__ ln_g, const float* __restrict__ ln_b,
                            const float* __restrict__ bn2g,
                            float* __restrict__ hn_out, float* __restrict__ vol)
{
  __shared__ uint4 w1s[48 * 64];                         // 49152 B
  __shared__ uint4 w2s[32 * 64];                         // 32768 B
  __shared__ uint4 wns[16 * 64];                         // 16384 B
  __shared__ __align__(16) uint32_t zbuf[16][2][96];     // 49152 B

  {
    const uint4* pk4 = (const uint4*)pk;
    for (int t = threadIdx.x; t < 6144; t += 1024) {
      uint4 v = pk4[t];
      if (t < 3072)      w1s[t] = v;
      else if (t < 5120) w2s[t - 3072] = v;
      else               wns[t - 5120] = v;
    }
  }
  __syncthreads();

  const int l  = threadIdx.x & 63;
  const int w  = threadIdx.x >> 6;
  const int gw = blockIdx.x * 16 + w;
  const int nw = gridDim.x * 16;
  const int p  = l & 31;           // channel-pair index for gather
  const int kb = l >> 5;           // corner parity for gather

  const float c0 = cmin[0], c1 = cmin[1], c2 = cmin[2];
  const float st0 = sstr[0], st1 = sstr[1], st2 = sstr[2];
  const float bia0 = b1[l],  bia1 = b1[64 + l];
  const float bib0 = b2[l],  bib1 = b2[64 + l];
  const float lg0 = ln_g[l], lg1 = ln_g[64 + l];
  const float lb0 = ln_b[l], lb1 = ln_b[64 + l];
  const float bnp = bn2g[l];

  for (int idx = gw; idx < NNODES / 2; idx += nw) {
    float cw[2][8]; int cf[2][8]; int bb[2];
    float hA[2], hB[2];

    // ---- per-node: corners, gather, h load, z-pack ----
    #pragma unroll
    for (int nd = 0; nd < 2; ++nd) {
      int n = 2 * idx + nd;
      float gx = (x[n * 3 + 0] - c0) / st0;
      float gy = (x[n * 3 + 1] - c1) / st1;
      float gz = (x[n * 3 + 2] - c2) / st2;
      float fx0 = floorf(gx), fy0 = floorf(gy), fz0 = floorf(gz);
      float fx = fminf(fmaxf(gx - fx0, 0.f), 1.f);
      float fy = fminf(fmaxf(gy - fy0, 0.f), 1.f);
      float fz = fminf(fmaxf(gz - fz0, 0.f), 1.f);
      int ix0 = (int)fx0, iy0 = (int)fy0, iz0 = (int)fz0;
      bb[nd] = nbat[n];

      #pragma unroll
      for (int k = 0; k < 8; ++k) {
        int xi = (k & 1) ? ix0 + 1 : ix0;
        int yi = (k & 2) ? iy0 + 1 : iy0;
        int zi = (k & 4) ? iz0 + 1 : iz0;
        float wx = (k & 1) ? fx : 1.f - fx;
        float wy = (k & 2) ? fy : 1.f - fy;
        float wz = (k & 4) ? fz : 1.f - fz;
        bool valid = (xi >= 0) & (xi < 64) & (yi >= 0) & (yi < 64) & (zi >= 0) & (zi < 64);
        int xc = min(max(xi, 0), 63), yc = min(max(yi, 0), 63), zc = min(max(zi, 0), 63);
        cw[nd][k] = valid ? wx * wy * wz : 0.f;
        cf[nd][k] = (zc << 12) | (yc << 6) | xc;
      }

      // gather (coalesced): lanes 0..31 corners {0,2,4,6}, lanes 32..63 corners {1,3,5,7}
      const uint32_t* gt = gridT + (size_t)bb[nd] * ((size_t)DHW * 32);
      float slo = 0.f, shi = 0.f;
      #pragma unroll
      for (int j = 0; j < 4; ++j) {
        int k = 2 * j + kb;
        h2 gv = as_h2(gt[(size_t)cf[nd][k] * 32 + p]);
        slo = fmaf(cw[nd][k], (float)gv.x, slo);
        shi = fmaf(cw[nd][k], (float)gv.y, shi);
      }
      slo += __shfl_xor(slo, 32);
      shi += __shfl_xor(shi, 32);

      hA[nd] = h[(size_t)n * NCH + l];
      hB[nd] = h[(size_t)n * NCH + 64 + l];

      uint32_t* zw = zbuf[w][nd];
      zw[l] = pack_h2(hA[nd], hB[nd]);        // pair m=l: (z[m], z[64+m])
      if (l < 32) zw[64 + p] = pack_h2(slo, shi);  // pair 64+p: (samp[2p], samp[2p+1])
    }
    asm volatile("s_waitcnt lgkmcnt(0)" ::: "memory");

    // ---- layer1: 192 -> 128 (fp16 dot2), silu ----
    float a00 = bia0, a01 = bia1, a10 = bia0, a11 = bia1;
    #pragma unroll 4
    for (int m2 = 0; m2 < 48; ++m2) {
      uint4 wv = w1s[m2 * 64 + l];
      uint2 z0 = *(const uint2*)&zbuf[w][0][2 * m2];
      uint2 z1 = *(const uint2*)&zbuf[w][1][2 * m2];
      a00 = dot2(z0.x, wv.x, a00); a01 = dot2(z0.x, wv.y, a01);
      a00 = dot2(z0.y, wv.z, a00); a01 = dot2(z0.y, wv.w, a01);
      a10 = dot2(z1.x, wv.x, a10); a11 = dot2(z1.x, wv.y, a11);
      a10 = dot2(z1.y, wv.z, a10); a11 = dot2(z1.y, wv.w, a11);
    }
    zbuf[w][0][l] = pack_h2(siluf(a00), siluf(a01));
    zbuf[w][1][l] = pack_h2(siluf(a10), siluf(a11));
    asm volatile("s_waitcnt lgkmcnt(0)" ::: "memory");

    // ---- layer2: 128 -> 128 ----
    float m00 = bib0, m01 = bib1, m10 = bib0, m11 = bib1;
    #pragma unroll 4
    for (int m2 = 0; m2 < 32; ++m2) {
      uint4 wv = w2s[m2 * 64 + l];
      uint2 z0 = *(const uint2*)&zbuf[w][0][2 * m2];
      uint2 z1 = *(const uint2*)&zbuf[w][1][2 * m2];
      m00 = dot2(z0.x, wv.x, m00); m01 = dot2(z0.x, wv.y, m01);
      m00 = dot2(z0.y, wv.z, m00); m01 = dot2(z0.y, wv.w, m01);
      m10 = dot2(z1.x, wv.x, m10); m11 = dot2(z1.x, wv.y, m11);
      m10 = dot2(z1.y, wv.z, m10); m11 = dot2(z1.y, wv.w, m11);
    }

    // ---- residual + LayerNorm + store hn ----
    float prj[2];
    #pragma unroll
    for (int nd = 0; nd < 2; ++nd) {
      float hn0 = hA[nd] + (nd ? m10 : m00);
      float hn1 = hB[nd] + (nd ? m11 : m01);
      float ss = hn0 + hn1, qq = hn0 * hn0 + hn1 * hn1;
      #pragma unroll
      for (int off = 32; off >= 1; off >>= 1) {
        ss += __shfl_xor(ss, off, 64);
        qq += __shfl_xor(qq, off, 64);
      }
      float mu = ss * (1.f / 128.f);
      float var = qq * (1.f / 128.f) - mu * mu;
      float rstd = rsqrtf(var + 1e-5f);
      float yA = (hn0 - mu) * rstd * lg0 + lb0;
      float yB = (hn1 - mu) * rstd * lg1 + lb1;
      int n = 2 * idx + nd;
      hn_out[(size_t)n * NCH + l] = yA;
      hn_out[(size_t)n * NCH + 64 + l] = yB;
      zbuf[w][nd][l] = pack_h2(yA, yB);
      prj[nd] = bnp;
    }
    asm volatile("s_waitcnt lgkmcnt(0)" ::: "memory");

    // ---- proj: 128 -> 64 ----
    #pragma unroll 4
    for (int m2 = 0; m2 < 16; ++m2) {
      uint4 wv = wns[m2 * 64 + l];
      uint4 z0 = *(const uint4*)&zbuf[w][0][4 * m2];
      uint4 z1 = *(const uint4*)&zbuf[w][1][4 * m2];
      prj[0] = dot2(z0.x, wv.x, prj[0]); prj[0] = dot2(z0.y, wv.y, prj[0]);
      prj[0] = dot2(z0.z, wv.z, prj[0]); prj[0] = dot2(z0.w, wv.w, prj[0]);
      prj[1] = dot2(z1.x, wv.x, prj[1]); prj[1] = dot2(z1.y, wv.y, prj[1]);
      prj[1] = dot2(z1.z, wv.z, prj[1]); prj[1] = dot2(z1.w, wv.w, prj[1]);
    }

    // ---- scatter-add to vol (channel-last) ----
    #pragma unroll
    for (int nd = 0; nd < 2; ++nd) {
      size_t vb = (size_t)bb[nd] * DHW;
      #pragma unroll
      for (int k = 0; k < 8; ++k) {
        if (cw[nd][k] != 0.f)
          atomicAdd(&vol[(vb + (size_t)cf[nd][k]) * 64 + l], cw[nd][k] * prj[nd]);
      }
    }
  }
}

// ---------------- per-voxel MLP kernel ----------------
__global__ void voxel_kernel(const float* __restrict__ grid, const float* __restrict__ vol,
                             const float* __restrict__ wc1, const float* __restrict__ bc1,
                             const float* __restrict__ wc2, const float* __restrict__ bc2,
                             float* __restrict__ gr_out, float* __restrict__ partials)
{
  __shared__ float w1t[128 * 64];   // [c][o] transposed wc1
  __shared__ float w2s[64 * 64];    // [o][j] original wc2
  __shared__ float b1s[64], b2s[64];

  for (int t = threadIdx.x; t < 8192; t += 256) {
    int o = t >> 7, c = t & 127;
    w1t[c * 64 + o] = wc1[t];
  }
  for (int t = threadIdx.x; t < 4096; t += 256) w2s[t] = wc2[t];
  if (threadIdx.x < 64) { b1s[threadIdx.x] = bc1[threadIdx.x]; b2s[threadIdx.x] = bc2[threadIdx.x]; }
  __syncthreads();

  const int v = blockIdx.x * 256 + threadIdx.x;   // 0 .. 1048575
  const int b = v >> 18;
  const int dhw = v & (DHW - 1);
  const float* gvox = grid + (size_t)(b * 64) * DHW + dhw;

  float acc[64];
  #pragma unroll
  for (int o = 0; o < 64; ++o) acc[o] = b1s[o];

  #pragma unroll 4
  for (int c = 0; c < 64; ++c) {
    float gc = gvox[(size_t)c * DHW];
    const float4* wr = (const float4*)&w1t[c * 64];
    #pragma unroll
    for (int o4 = 0; o4 < 16; ++o4) {
      float4 w4 = wr[o4];
      acc[o4 * 4 + 0] = fmaf(gc, w4.x, acc[o4 * 4 + 0]);
      acc[o4 * 4 + 1] = fmaf(gc, w4.y, acc[o4 * 4 + 1]);
      acc[o4 * 4 + 2] = fmaf(gc, w4.z, acc[o4 * 4 + 2]);
      acc[o4 * 4 + 3] = fmaf(gc, w4.w, acc[o4 * 4 + 3]);
    }
  }
  const float4* vv4 = (const float4*)(vol + (size_t)v * 64);
  #pragma unroll 2
  for (int c4 = 0; c4 < 16; ++c4) {
    float4 vv = vv4[c4];
    const float* vc = (const float*)&vv;
    #pragma unroll
    for (int j = 0; j < 4; ++j) {
      float vcj = vc[j];
      const float4* wr = (const float4*)&w1t[(64 + c4 * 4 + j) * 64];
      #pragma unroll
      for (int o4 = 0; o4 < 16; ++o4) {
        float4 w4 = wr[o4];
        acc[o4 * 4 + 0] = fmaf(vcj, w4.x, acc[o4 * 4 + 0]);
        acc[o4 * 4 + 1] = fmaf(vcj, w4.y, acc[o4 * 4 + 1]);
        acc[o4 * 4 + 2] = fmaf(vcj, w4.z, acc[o4 * 4 + 2]);
        acc[o4 * 4 + 3] = fmaf(vcj, w4.w, acc[o4 * 4 + 3]);
      }
    }
  }
  #pragma unroll
  for (int o = 0; o < 64; ++o) acc[o] = siluf(acc[o]);

  float* pbase = partials + (size_t)(v >> 6) * 128;
  for (int o = 0; o < 64; ++o) {
    float a2 = b2s[o];
    const float4* wr = (const float4*)&w2s[o * 64];
    #pragma unroll
    for (int j4 = 0; j4 < 16; ++j4) {
      float4 w4 = wr[j4];
      a2 = fmaf(acc[j4 * 4 + 0], w4.x, a2);
      a2 = fmaf(acc[j4 * 4 + 1], w4.y, a2);
      a2 = fmaf(acc[j4 * 4 + 2], w4.z, a2);
      a2 = fmaf(acc[j4 * 4 + 3], w4.w, a2);
    }
    float gc = gvox[(size_t)o * DHW];
    float grv = gc + a2;
    gr_out[(size_t)(b * 64 + o) * DHW + dhw] = grv;
    float sv = grv, qv = grv * grv;
    #pragma unroll
    for (int off = 32; off >= 1; off >>= 1) {
      sv += __shfl_xor(sv, off, 64);
      qv += __shfl_xor(qv, off, 64);
    }
    if ((threadIdx.x & 63) == 0) { pbase[2 * o] = sv; pbase[2 * o + 1] = qv; }
  }
}

// ---------------- reduce partials -> per (b,c) scale/shift ----------------
__global__ void stats_kernel(const float* __restrict__ partials, const float* __restrict__ in_g,
                             const float* __restrict__ in_b, float* __restrict__ stats)
{
  int bo = blockIdx.x;            // b*64 + o
  int b = bo >> 6, o = bo & 63;
  float s = 0.f, q = 0.f;
  for (int k = threadIdx.x; k < 4096; k += 256) {
    const float* pp = partials + (size_t)(b * 4096 + k) * 128 + 2 * o;
    s += pp[0]; q += pp[1];
  }
  __shared__ float sred[256], qred[256];
  sred[threadIdx.x] = s; qred[threadIdx.x] = q;
  __syncthreads();
  for (int st = 128; st >= 1; st >>= 1) {
    if (threadIdx.x < st) { sred[threadIdx.x] += sred[threadIdx.x + st]; qred[threadIdx.x] += qred[threadIdx.x + st]; }
    __syncthreads();
  }
  if (threadIdx.x == 0) {
    float mu = sred[0] * (1.f / (float)DHW);
    float var = qred[0] * (1.f / (float)DHW) - mu * mu;
    float rstd = rsqrtf(var + 1e-5f);
    float scale = rstd * in_g[o];
    stats[2 * bo] = scale;
    stats[2 * bo + 1] = in_b[o] - mu * scale;
  }
}

// ---------------- apply instance norm in place ----------------
__global__ void norm_kernel(float* __restrict__ gr, const float* __restrict__ stats)
{
  const size_t total4 = (size_t)NBATCH * 64 * DHW / 4;
  size_t stride = (size_t)gridDim.x * 256;
  for (size_t i = blockIdx.x * 256 + threadIdx.x; i < total4; i += stride) {
    int bo = (int)(i >> 16);
    float scale = stats[2 * bo], shift = stats[2 * bo + 1];
    float4 v = ((float4*)gr)[i];
    v.x = fmaf(v.x, scale, shift);
    v.y = fmaf(v.y, scale, shift);
    v.z = fmaf(v.z, scale, shift);
    v.w = fmaf(v.w, scale, shift);
    ((float4*)gr)[i] = v;
  }
}

extern "C" void kernel_launch(void* const* d_in, const int* in_sizes, int n_in,
                              void* d_out, int out_size, void* d_ws, size_t ws_size,
                              hipStream_t stream)
{
  const float* h     = (const float*)d_in[0];
  const float* x     = (const float*)d_in[1];
  const float* grid  = (const float*)d_in[2];
  const int*   nbat  = (const int*)d_in[3];
  const float* cmin  = (const float*)d_in[4];
  const float* sstr  = (const float*)d_in[5];
  const float* w1    = (const float*)d_in[6];
  const float* b1    = (const float*)d_in[7];
  const float* w2    = (const float*)d_in[8];
  const float* b2    = (const float*)d_in[9];
  const float* ln_g  = (const float*)d_in[10];
  const float* ln_b  = (const float*)d_in[11];
  const float* wn2g  = (const float*)d_in[12];
  const float* bn2g  = (const float*)d_in[13];
  const float* wc1   = (const float*)d_in[14];
  const float* bc1   = (const float*)d_in[15];
  const float* wc2   = (const float*)d_in[16];
  const float* bc2   = (const float*)d_in[17];
  const float* in_g  = (const float*)d_in[18];
  const float* in_b  = (const float*)d_in[19];

  float* hn_out = (float*)d_out;
  float* gr_out = (float*)d_out + (size_t)NNODES * NCH;

  char* ws = (char*)d_ws;
  float*    vol      = (float*)ws;                     // 268 MB, zeroed each call
  float*    partials = (float*)(ws + PART_OFF);        // 8 MB
  float*    stats    = (float*)(ws + STAT_OFF);        // 2 KB
  uint32_t* pk       = (uint32_t*)(ws + PK_OFF);       // 96 KB
  uint32_t* gridT    = (uint32_t*)(ws + GT_OFF);       // 128 MB

  (void)hipMemsetAsync(vol, 0, VOL_BYTES, stream);
  pack_weights<<<96, 256, 0, stream>>>(w1, w2, wn2g, pk);
  transpose_kernel<<<16384, 256, 0, stream>>>(grid, gridT);
  node_kernel<<<256, 1024, 0, stream>>>(h, x, gridT, nbat, cmin, sstr, pk,
                                        b1, b2, ln_g, ln_b, bn2g, hn_out, vol);
  voxel_kernel<<<4096, 256, 0, stream>>>(grid, vol, wc1, bc1, wc2, bc2, gr_out, partials);
  stats_kernel<<<256, 256, 0, stream>>>(partials, in_g, in_b, stats);
  norm_kernel<<<4096, 256, 0, stream>>>(gr_out, stats);
}

// Round 6
// 960.464 us; speedup vs baseline: 1.9703x; 1.3856x over previous
//
#include <hip/hip_runtime.h>
#include <cstdint>

#define NNODES 200000
#define NCH 128
#define CGC 64
#define NBATCH 4
#define DHW 262144      // 64*64*64
#define K1 192
#define HID 128

#define VOL_BYTES   268435456ull                 // 4*DHW*64*4
#define PART_OFF    268435456ull
#define PART_BYTES  8388608ull                   // 16384 blocks * 128 f32
#define STAT_OFF    (PART_OFF + PART_BYTES)
#define PK_OFF      (STAT_OFF + 2048ull)
#define PK_BYTES    98304ull                     // 24576 u32
#define GT_OFF      (PK_OFF + PK_BYTES)
#define GT_BYTES    134217728ull                 // 4*DHW*32*4  (fp16 pairs)
#define WF_OFF      (GT_OFF + GT_BYTES)
#define WF_BYTES    24576ull                     // 6144 u32 (wc1/wc2 MFMA fragments)

typedef _Float16 h2 __attribute__((ext_vector_type(2)));
typedef __fp16  fp16x2 __attribute__((ext_vector_type(2)));
typedef _Float16 f16x8 __attribute__((ext_vector_type(8)));
typedef float f32x4 __attribute__((ext_vector_type(4)));

__device__ __forceinline__ uint32_t pack_h2(float a, float b){
  fp16x2 p = __builtin_amdgcn_cvt_pkrtz(a, b);
  return __builtin_bit_cast(uint32_t, p);
}
__device__ __forceinline__ h2 as_h2(uint32_t w){ return __builtin_bit_cast(h2, w); }
__device__ __forceinline__ float dot2(uint32_t zp, uint32_t wp, float acc){
  return __builtin_amdgcn_fdot2(as_h2(zp), as_h2(wp), acc, false);
}
__device__ __forceinline__ float siluf(float a){ return a / (1.f + __expf(-a)); }
__device__ __forceinline__ f32x4 mfma16(uint4 a, uint4 b, f32x4 c){
  return __builtin_amdgcn_mfma_f32_16x16x32_f16(
      __builtin_bit_cast(f16x8, a), __builtin_bit_cast(f16x8, b), c, 0, 0, 0);
}

// ---------------- pack MLP weights to fp16 pairs (node path) ----------------
__global__ void pack_weights(const float* __restrict__ w1, const float* __restrict__ w2,
                             const float* __restrict__ wn2g, uint32_t* __restrict__ pk)
{
  int t = blockIdx.x * 256 + threadIdx.x;
  if (t < 12288) {
    int q = t & 3, l = (t >> 2) & 63, m2 = t >> 8;
    int m = 2 * m2 + (q >> 1);
    int j = (q & 1) ? 64 + l : l;
    int i0 = (m < 64) ? m : 128 + 2 * (m - 64);
    int i1 = (m < 64) ? 64 + m : 128 + 2 * (m - 64) + 1;
    pk[t] = pack_h2(w1[j * K1 + i0], w1[j * K1 + i1]);
  } else if (t < 20480) {
    int u = t - 12288;
    int q = u & 3, l = (u >> 2) & 63, m2 = u >> 8;
    int m = 2 * m2 + (q >> 1);
    int j = (q & 1) ? 64 + l : l;
    pk[t] = pack_h2(w2[j * HID + m], w2[j * HID + 64 + m]);
  } else if (t < 24576) {
    int u = t - 20480;
    int q = u & 3, o = (u >> 2) & 63, m2 = u >> 8;
    int m = 4 * m2 + q;
    pk[t] = pack_h2(wn2g[o * HID + m], wn2g[o * HID + 64 + m]);
  }
}

// ---------------- pack wc1/wc2 into MFMA A-fragments ----------------
// A-layout for mfma_f32_16x16x32_f16: lane l holds A[row = l&15][k = (l>>4)*8 + i], i=0..7,
// packed as 4 u32 of consecutive-k fp16 pairs.
// layer1: frag f = tt*4+s (o-tile tt, K-step s, K=128). layer2: f = tt*2+s (K=64).
__global__ void pack_wc(const float* __restrict__ wc1, const float* __restrict__ wc2,
                        uint32_t* __restrict__ wf)
{
  int t = blockIdx.x * 256 + threadIdx.x;
  if (t < 4096) {
    int q = t & 3, lane = (t >> 2) & 63, f = t >> 8;   // f 0..15
    int s = f & 3, tt = f >> 2;
    int o = tt * 16 + (lane & 15);
    int k = s * 32 + (lane >> 4) * 8 + 2 * q;
    wf[t] = pack_h2(wc1[o * 128 + k], wc1[o * 128 + k + 1]);
  } else if (t < 6144) {
    int u = t - 4096;
    int q = u & 3, lane = (u >> 2) & 63, f = u >> 8;   // f 0..7
    int s = f & 1, tt = f >> 1;
    int o = tt * 16 + (lane & 15);
    int k = s * 32 + (lane >> 4) * 8 + 2 * q;
    wf[t] = pack_h2(wc2[o * 64 + k], wc2[o * 64 + k + 1]);
  }
}

// ---------------- transpose grid -> channel-last fp16 pairs ----------------
__global__ void transpose_kernel(const float* __restrict__ grid, uint32_t* __restrict__ gt)
{
  __shared__ float tile[64][65];
  int bx = blockIdx.x;                  // 0..16383
  int b = bx >> 12;
  int dhw0 = (bx & 4095) << 6;
  const float* gbase = grid + ((size_t)b * 64) * DHW + dhw0;
  int c0 = threadIdx.x >> 6, d = threadIdx.x & 63;
  #pragma unroll
  for (int i = 0; i < 16; ++i)
    tile[i * 4 + c0][d] = gbase[(size_t)(i * 4 + c0) * DHW + d];
  __syncthreads();
  uint32_t* tb = gt + ((size_t)b * DHW + dhw0) * 32;
  int p = threadIdx.x & 31, r0 = threadIdx.x >> 5;   // r0 0..7
  #pragma unroll
  for (int i = 0; i < 8; ++i) {
    int dd = i * 8 + r0;
    tb[(size_t)dd * 32 + p] = pack_h2(tile[2 * p][dd], tile[2 * p + 1][dd]);
  }
}

// ---------------- per-node fused kernel ----------------
// 1 wave per 2 nodes. lane l owns output channels (l, l+64).
__launch_bounds__(1024)
__global__ void node_kernel(const float* __restrict__ h, const float* __restrict__ x,
                            const uint32_t* __restrict__ gridT, const int* __restrict__ nbat,
                            const float* __restrict__ cmin, const float* __restrict__ sstr,
                            const uint32_t* __restrict__ pk,
                            const float* __restrict__ b1, const float* __restrict__ b2,
                            const float* __restrict__ ln_g, const float* __restrict__ ln_b,
                            const float* __restrict__ bn2g,
                            float* __restrict__ hn_out, float* __restrict__ vol)
{
  __shared__ uint4 w1s[48 * 64];                         // 49152 B
  __shared__ uint4 w2s[32 * 64];                         // 32768 B
  __shared__ uint4 wns[16 * 64];                         // 16384 B
  __shared__ __align__(16) uint32_t zbuf[16][2][96];     // 49152 B

  {
    const uint4* pk4 = (const uint4*)pk;
    for (int t = threadIdx.x; t < 6144; t += 1024) {
      uint4 v = pk4[t];
      if (t < 3072)      w1s[t] = v;
      else if (t < 5120) w2s[t - 3072] = v;
      else               wns[t - 5120] = v;
    }
  }
  __syncthreads();

  const int l  = threadIdx.x & 63;
  const int w  = threadIdx.x >> 6;
  const int gw = blockIdx.x * 16 + w;
  const int nw = gridDim.x * 16;
  const int p  = l & 31;           // channel-pair index for gather
  const int kb = l >> 5;           // corner parity for gather

  const float c0 = cmin[0], c1 = cmin[1], c2 = cmin[2];
  const float st0 = sstr[0], st1 = sstr[1], st2 = sstr[2];
  const float bia0 = b1[l],  bia1 = b1[64 + l];
  const float bib0 = b2[l],  bib1 = b2[64 + l];
  const float lg0 = ln_g[l], lg1 = ln_g[64 + l];
  const float lb0 = ln_b[l], lb1 = ln_b[64 + l];
  const float bnp = bn2g[l];

  for (int idx = gw; idx < NNODES / 2; idx += nw) {
    float cw[2][8]; int cf[2][8]; int bb[2];
    float hA[2], hB[2];

    #pragma unroll
    for (int nd = 0; nd < 2; ++nd) {
      int n = 2 * idx + nd;
      float gx = (x[n * 3 + 0] - c0) / st0;
      float gy = (x[n * 3 + 1] - c1) / st1;
      float gz = (x[n * 3 + 2] - c2) / st2;
      float fx0 = floorf(gx), fy0 = floorf(gy), fz0 = floorf(gz);
      float fx = fminf(fmaxf(gx - fx0, 0.f), 1.f);
      float fy = fminf(fmaxf(gy - fy0, 0.f), 1.f);
      float fz = fminf(fmaxf(gz - fz0, 0.f), 1.f);
      int ix0 = (int)fx0, iy0 = (int)fy0, iz0 = (int)fz0;
      bb[nd] = nbat[n];

      #pragma unroll
      for (int k = 0; k < 8; ++k) {
        int xi = (k & 1) ? ix0 + 1 : ix0;
        int yi = (k & 2) ? iy0 + 1 : iy0;
        int zi = (k & 4) ? iz0 + 1 : iz0;
        float wx = (k & 1) ? fx : 1.f - fx;
        float wy = (k & 2) ? fy : 1.f - fy;
        float wz = (k & 4) ? fz : 1.f - fz;
        bool valid = (xi >= 0) & (xi < 64) & (yi >= 0) & (yi < 64) & (zi >= 0) & (zi < 64);
        int xc = min(max(xi, 0), 63), yc = min(max(yi, 0), 63), zc = min(max(zi, 0), 63);
        cw[nd][k] = valid ? wx * wy * wz : 0.f;
        cf[nd][k] = (zc << 12) | (yc << 6) | xc;
      }

      const uint32_t* gt = gridT + (size_t)bb[nd] * ((size_t)DHW * 32);
      float slo = 0.f, shi = 0.f;
      #pragma unroll
      for (int j = 0; j < 4; ++j) {
        int k = 2 * j + kb;
        h2 gv = as_h2(gt[(size_t)cf[nd][k] * 32 + p]);
        slo = fmaf(cw[nd][k], (float)gv.x, slo);
        shi = fmaf(cw[nd][k], (float)gv.y, shi);
      }
      slo += __shfl_xor(slo, 32);
      shi += __shfl_xor(shi, 32);

      hA[nd] = h[(size_t)n * NCH + l];
      hB[nd] = h[(size_t)n * NCH + 64 + l];

      uint32_t* zw = zbuf[w][nd];
      zw[l] = pack_h2(hA[nd], hB[nd]);
      if (l < 32) zw[64 + p] = pack_h2(slo, shi);
    }
    asm volatile("s_waitcnt lgkmcnt(0)" ::: "memory");

    float a00 = bia0, a01 = bia1, a10 = bia0, a11 = bia1;
    #pragma unroll 4
    for (int m2 = 0; m2 < 48; ++m2) {
      uint4 wv = w1s[m2 * 64 + l];
      uint2 z0 = *(const uint2*)&zbuf[w][0][2 * m2];
      uint2 z1 = *(const uint2*)&zbuf[w][1][2 * m2];
      a00 = dot2(z0.x, wv.x, a00); a01 = dot2(z0.x, wv.y, a01);
      a00 = dot2(z0.y, wv.z, a00); a01 = dot2(z0.y, wv.w, a01);
      a10 = dot2(z1.x, wv.x, a10); a11 = dot2(z1.x, wv.y, a11);
      a10 = dot2(z1.y, wv.z, a10); a11 = dot2(z1.y, wv.w, a11);
    }
    zbuf[w][0][l] = pack_h2(siluf(a00), siluf(a01));
    zbuf[w][1][l] = pack_h2(siluf(a10), siluf(a11));
    asm volatile("s_waitcnt lgkmcnt(0)" ::: "memory");

    float m00 = bib0, m01 = bib1, m10 = bib0, m11 = bib1;
    #pragma unroll 4
    for (int m2 = 0; m2 < 32; ++m2) {
      uint4 wv = w2s[m2 * 64 + l];
      uint2 z0 = *(const uint2*)&zbuf[w][0][2 * m2];
      uint2 z1 = *(const uint2*)&zbuf[w][1][2 * m2];
      m00 = dot2(z0.x, wv.x, m00); m01 = dot2(z0.x, wv.y, m01);
      m00 = dot2(z0.y, wv.z, m00); m01 = dot2(z0.y, wv.w, m01);
      m10 = dot2(z1.x, wv.x, m10); m11 = dot2(z1.x, wv.y, m11);
      m10 = dot2(z1.y, wv.z, m10); m11 = dot2(z1.y, wv.w, m11);
    }

    float prj[2];
    #pragma unroll
    for (int nd = 0; nd < 2; ++nd) {
      float hn0 = hA[nd] + (nd ? m10 : m00);
      float hn1 = hB[nd] + (nd ? m11 : m01);
      float ss = hn0 + hn1, qq = hn0 * hn0 + hn1 * hn1;
      #pragma unroll
      for (int off = 32; off >= 1; off >>= 1) {
        ss += __shfl_xor(ss, off, 64);
        qq += __shfl_xor(qq, off, 64);
      }
      float mu = ss * (1.f / 128.f);
      float var = qq * (1.f / 128.f) - mu * mu;
      float rstd = rsqrtf(var + 1e-5f);
      float yA = (hn0 - mu) * rstd * lg0 + lb0;
      float yB = (hn1 - mu) * rstd * lg1 + lb1;
      int n = 2 * idx + nd;
      hn_out[(size_t)n * NCH + l] = yA;
      hn_out[(size_t)n * NCH + 64 + l] = yB;
      zbuf[w][nd][l] = pack_h2(yA, yB);
      prj[nd] = bnp;
    }
    asm volatile("s_waitcnt lgkmcnt(0)" ::: "memory");

    #pragma unroll 4
    for (int m2 = 0; m2 < 16; ++m2) {
      uint4 wv = wns[m2 * 64 + l];
      uint4 z0 = *(const uint4*)&zbuf[w][0][4 * m2];
      uint4 z1 = *(const uint4*)&zbuf[w][1][4 * m2];
      prj[0] = dot2(z0.x, wv.x, prj[0]); prj[0] = dot2(z0.y, wv.y, prj[0]);
      prj[0] = dot2(z0.z, wv.z, prj[0]); prj[0] = dot2(z0.w, wv.w, prj[0]);
      prj[1] = dot2(z1.x, wv.x, prj[1]); prj[1] = dot2(z1.y, wv.y, prj[1]);
      prj[1] = dot2(z1.z, wv.z, prj[1]); prj[1] = dot2(z1.w, wv.w, prj[1]);
    }

    #pragma unroll
    for (int nd = 0; nd < 2; ++nd) {
      size_t vb = (size_t)bb[nd] * DHW;
      #pragma unroll
      for (int k = 0; k < 8; ++k) {
        if (cw[nd][k] != 0.f)
          atomicAdd(&vol[(vb + (size_t)cf[nd][k]) * 64 + l], cw[nd][k] * prj[nd]);
      }
    }
  }
}

// ---------------- per-voxel MLP kernel (MFMA) ----------------
// block = 256 threads = 4 waves, 64 voxels (16/wave). Weights live in registers
// as A-fragments; per-block LDS: transposed fp16 feature tile + per-wave g1 relayout.
__launch_bounds__(256, 2)
__global__ void voxel_kernel(const float* __restrict__ grid, const float* __restrict__ vol,
                             const uint32_t* __restrict__ wf, const float* __restrict__ bc1,
                             const float* __restrict__ bc2,
                             float* __restrict__ gr_out, float* __restrict__ partials)
{
  __shared__ __align__(16) uint32_t xt[64][68];     // [v][c2], c2 = fp16 pair of channels
  __shared__ __align__(16) uint32_t g1b[4][16][36]; // per-wave [v][o2]
  __shared__ float part_s[4][128];

  const int tid = threadIdx.x;
  const int lane = tid & 63, wv = tid >> 6;
  const int g = lane >> 4, vl = lane & 15;
  const int b = blockIdx.x >> 12;
  const int dhw0 = (blockIdx.x & 4095) << 6;
  const float* gb = grid + (size_t)(b * 64) * DHW + dhw0;

  // ---- stage grid half: thread (c2 = tid>>3 in 0..31, vq = tid&7 voxel octet) ----
  {
    int c2 = tid >> 3, vq = tid & 7;
    const float* p0 = gb + (size_t)(2 * c2) * DHW + 8 * vq;
    const float* p1 = gb + (size_t)(2 * c2 + 1) * DHW + 8 * vq;
    float4 a0 = *(const float4*)p0;
    float4 b0 = *(const float4*)(p0 + 4);
    float4 a1 = *(const float4*)p1;
    float4 b1 = *(const float4*)(p1 + 4);
    int v0 = 8 * vq;
    xt[v0 + 0][c2] = pack_h2(a0.x, a1.x);
    xt[v0 + 1][c2] = pack_h2(a0.y, a1.y);
    xt[v0 + 2][c2] = pack_h2(a0.z, a1.z);
    xt[v0 + 3][c2] = pack_h2(a0.w, a1.w);
    xt[v0 + 4][c2] = pack_h2(b0.x, b1.x);
    xt[v0 + 5][c2] = pack_h2(b0.y, b1.y);
    xt[v0 + 6][c2] = pack_h2(b0.z, b1.z);
    xt[v0 + 7][c2] = pack_h2(b0.w, b1.w);
  }
  // ---- stage vol half (channel-last already): thread (v = u>>4, c4 = u&15) ----
  {
    const float* vb = vol + ((size_t)b * DHW + dhw0) * 64;
    #pragma unroll
    for (int it = 0; it < 4; ++it) {
      int u = it * 256 + tid;
      int v = u >> 4, c4 = u & 15;
      float4 a = *(const float4*)(vb + (size_t)v * 64 + 4 * c4);
      uint2 pr;
      pr.x = pack_h2(a.x, a.y);
      pr.y = pack_h2(a.z, a.w);
      *(uint2*)&xt[v][32 + 2 * c4] = pr;
    }
  }

  // ---- weight fragments into registers ----
  const uint4* wf4 = (const uint4*)wf;
  uint4 w1f[4][4], w2f[4][2];
  #pragma unroll
  for (int t = 0; t < 4; ++t)
    #pragma unroll
    for (int s = 0; s < 4; ++s)
      w1f[t][s] = wf4[(t * 4 + s) * 64 + lane];
  #pragma unroll
  for (int t = 0; t < 4; ++t)
    #pragma unroll
    for (int s = 0; s < 2; ++s)
      w2f[t][s] = wf4[1024 + (t * 2 + s) * 64 + lane];

  f32x4 acc1[4];
  #pragma unroll
  for (int t = 0; t < 4; ++t) {
    #pragma unroll
    for (int r = 0; r < 4; ++r) acc1[t][r] = bc1[t * 16 + g * 4 + r];
  }

  __syncthreads();

  // ---- layer1: D[o][v] = Wc1 * X, K=128 ----
  const int v = wv * 16 + vl;
  #pragma unroll
  for (int s = 0; s < 4; ++s) {
    uint4 xb = *(const uint4*)&xt[v][s * 16 + g * 4];
    #pragma unroll
    for (int t = 0; t < 4; ++t) acc1[t] = mfma16(w1f[t][s], xb, acc1[t]);
  }

  // ---- silu + relayout g1 through per-wave LDS ----
  #pragma unroll
  for (int t = 0; t < 4; ++t) {
    uint2 pr;
    pr.x = pack_h2(siluf(acc1[t][0]), siluf(acc1[t][1]));
    pr.y = pack_h2(siluf(acc1[t][2]), siluf(acc1[t][3]));
    *(uint2*)&g1b[wv][vl][t * 8 + g * 2] = pr;
  }
  asm volatile("s_waitcnt lgkmcnt(0)" ::: "memory");

  // ---- layer2: K=64 ----
  f32x4 acc2[4];
  #pragma unroll
  for (int t = 0; t < 4; ++t) {
    #pragma unroll
    for (int r = 0; r < 4; ++r) acc2[t][r] = bc2[t * 16 + g * 4 + r];
  }
  #pragma unroll
  for (int s = 0; s < 2; ++s) {
    uint4 gv = *(const uint4*)&g1b[wv][vl][s * 16 + g * 4];
    #pragma unroll
    for (int t = 0; t < 4; ++t) acc2[t] = mfma16(w2f[t][s], gv, acc2[t]);
  }

  // ---- residual + store + per-block stats ----
  const int dhw = dhw0 + v;
  #pragma unroll
  for (int t = 0; t < 4; ++t) {
    #pragma unroll
    for (int r = 0; r < 4; ++r) {
      int o = t * 16 + g * 4 + r;
      size_t gi = (size_t)(b * 64 + o) * DHW + dhw;
      float grv = grid[gi] + acc2[t][r];
      gr_out[gi] = grv;
      float sv = grv, qv = grv * grv;
      sv += __shfl_xor(sv, 1, 64); qv += __shfl_xor(qv, 1, 64);
      sv += __shfl_xor(sv, 2, 64); qv += __shfl_xor(qv, 2, 64);
      sv += __shfl_xor(sv, 4, 64); qv += __shfl_xor(qv, 4, 64);
      sv += __shfl_xor(sv, 8, 64); qv += __shfl_xor(qv, 8, 64);
      if (vl == 0) { part_s[wv][2 * o] = sv; part_s[wv][2 * o + 1] = qv; }
    }
  }
  __syncthreads();
  if (tid < 128)
    partials[(size_t)blockIdx.x * 128 + tid] =
        part_s[0][tid] + part_s[1][tid] + part_s[2][tid] + part_s[3][tid];
}

// ---------------- reduce partials -> per (b,c) scale/shift ----------------
__global__ void stats_kernel(const float* __restrict__ partials, const float* __restrict__ in_g,
                             const float* __restrict__ in_b, float* __restrict__ stats)
{
  int bo = blockIdx.x;            // b*64 + o
  int b = bo >> 6, o = bo & 63;
  float s = 0.f, q = 0.f;
  for (int k = threadIdx.x; k < 4096; k += 256) {
    const float* pp = partials + (size_t)(b * 4096 + k) * 128 + 2 * o;
    s += pp[0]; q += pp[1];
  }
  __shared__ float sred[256], qred[256];
  sred[threadIdx.x] = s; qred[threadIdx.x] = q;
  __syncthreads();
  for (int st = 128; st >= 1; st >>= 1) {
    if (threadIdx.x < st) { sred[threadIdx.x] += sred[threadIdx.x + st]; qred[threadIdx.x] += qred[threadIdx.x + st]; }
    __syncthreads();
  }
  if (threadIdx.x == 0) {
    float mu = sred[0] * (1.f / (float)DHW);
    float var = qred[0] * (1.f / (float)DHW) - mu * mu;
    float rstd = rsqrtf(var + 1e-5f);
    float scale = rstd * in_g[o];
    stats[2 * bo] = scale;
    stats[2 * bo + 1] = in_b[o] - mu * scale;
  }
}

// ---------------- apply instance norm in place ----------------
__global__ void norm_kernel(float* __restrict__ gr, const float* __restrict__ stats)
{
  const size_t total4 = (size_t)NBATCH * 64 * DHW / 4;
  size_t stride = (size_t)gridDim.x * 256;
  for (size_t i = blockIdx.x * 256 + threadIdx.x; i < total4; i += stride) {
    int bo = (int)(i >> 16);
    float scale = stats[2 * bo], shift = stats[2 * bo + 1];
    float4 v = ((float4*)gr)[i];
    v.x = fmaf(v.x, scale, shift);
    v.y = fmaf(v.y, scale, shift);
    v.z = fmaf(v.z, scale, shift);
    v.w = fmaf(v.w, scale, shift);
    ((float4*)gr)[i] = v;
  }
}

extern "C" void kernel_launch(void* const* d_in, const int* in_sizes, int n_in,
                              void* d_out, int out_size, void* d_ws, size_t ws_size,
                              hipStream_t stream)
{
  const float* h     = (const float*)d_in[0];
  const float* x     = (const float*)d_in[1];
  const float* grid  = (const float*)d_in[2];
  const int*   nbat  = (const int*)d_in[3];
  const float* cmin  = (const float*)d_in[4];
  const float* sstr  = (const float*)d_in[5];
  const float* w1    = (const float*)d_in[6];
  const float* b1    = (const float*)d_in[7];
  const float* w2    = (const float*)d_in[8];
  const float* b2    = (const float*)d_in[9];
  const float* ln_g  = (const float*)d_in[10];
  const float* ln_b  = (const float*)d_in[11];
  const float* wn2g  = (const float*)d_in[12];
  const float* bn2g  = (const float*)d_in[13];
  const float* wc1   = (const float*)d_in[14];
  const float* bc1   = (const float*)d_in[15];
  const float* wc2   = (const float*)d_in[16];
  const float* bc2   = (const float*)d_in[17];
  const float* in_g  = (const float*)d_in[18];
  const float* in_b  = (const float*)d_in[19];

  float* hn_out = (float*)d_out;
  float* gr_out = (float*)d_out + (size_t)NNODES * NCH;

  char* ws = (char*)d_ws;
  float*    vol      = (float*)ws;                     // 268 MB, zeroed each call
  float*    partials = (float*)(ws + PART_OFF);        // 8 MB
  float*    stats    = (float*)(ws + STAT_OFF);        // 2 KB
  uint32_t* pk       = (uint32_t*)(ws + PK_OFF);       // 96 KB
  uint32_t* gridT    = (uint32_t*)(ws + GT_OFF);       // 128 MB
  uint32_t* wf       = (uint32_t*)(ws + WF_OFF);       // 24 KB

  (void)hipMemsetAsync(vol, 0, VOL_BYTES, stream);
  pack_weights<<<96, 256, 0, stream>>>(w1, w2, wn2g, pk);
  pack_wc<<<24, 256, 0, stream>>>(wc1, wc2, wf);
  transpose_kernel<<<16384, 256, 0, stream>>>(grid, gridT);
  node_kernel<<<256, 1024, 0, stream>>>(h, x, gridT, nbat, cmin, sstr, pk,
                                        b1, b2, ln_g, ln_b, bn2g, hn_out, vol);
  voxel_kernel<<<16384, 256, 0, stream>>>(grid, vol, wf, bc1, bc2, gr_out, partials);
  stats_kernel<<<256, 256, 0, stream>>>(partials, in_g, in_b, stats);
  norm_kernel<<<4096, 256, 0, stream>>>(gr_out, stats);
}

// Round 8
// 749.773 us; speedup vs baseline: 2.5240x; 1.2810x over previous
//
#include <hip/hip_runtime.h>
#include <hip/hip_fp16.h>
#include <cstdint>

#define NNODES 200000
#define NCH 128
#define NBATCH 4
#define DHW 262144      // 64*64*64
#define K1 192

// ---- workspace layout (bytes) ----
#define VOLH_OFF  0ull
#define VOLH_BYTES 134217728ull                  // 4*DHW*32 pairs *4B (fp16x2)
#define PART_OFF  134217728ull                   // 16384 blocks * 128 f32 = 8MB
#define STAT_OFF  142606336ull                   // 2KB
#define NWF_OFF   142608384ull                   // 24576 u32 = 96KB (node MLP A-frags)
#define WF_OFF    142706688ull                   // 6144 u32 = 24KB (voxel A-frags)
#define PRJ_OFF   142731264ull                   // 200000*32 u32 = 25.6MB
#define CFG_OFF   168331264ull                   // 200000*8 int = 6.4MB
#define CWG_OFF   174731264ull                   // 200000*8 f32 = 6.4MB
#define ZG_OFF    181131264ull                   // 200000*96 u32 = 76.8MB
#define GT_OFF    257931264ull                   // 134MB gridT; grh overlays after gather

typedef _Float16 h2 __attribute__((ext_vector_type(2)));
typedef __fp16  fp16x2 __attribute__((ext_vector_type(2)));
typedef _Float16 f16x8 __attribute__((ext_vector_type(8)));
typedef float f32x4 __attribute__((ext_vector_type(4)));

__device__ __forceinline__ uint32_t pack_h2(float a, float b){
  fp16x2 p = __builtin_amdgcn_cvt_pkrtz(a, b);
  return __builtin_bit_cast(uint32_t, p);
}
__device__ __forceinline__ h2 as_h2(uint32_t w){ return __builtin_bit_cast(h2, w); }
__device__ __forceinline__ float siluf(float a){ return a / (1.f + __expf(-a)); }
__device__ __forceinline__ f32x4 mfma16(uint4 a, uint4 b, f32x4 c){
  return __builtin_amdgcn_mfma_f32_16x16x32_f16(
      __builtin_bit_cast(f16x8, a), __builtin_bit_cast(f16x8, b), c, 0, 0, 0);
}
__device__ __forceinline__ void atomic_pk_add_f16(uint32_t* addr, uint32_t val){
  asm volatile("global_atomic_pk_add_f16 %0, %1, off"
               :: "v"(addr), "v"(val) : "memory");
}

// ---------------- pack node-MLP weights into MFMA A-fragments ----------------
// A-frag: lane holds A[o = tt*16 + (lane&15)][k = s*32 + (lane>>4)*8 + 2q (+1)]
// layer1 (w1 [128][192]): f = tt*6+s, u32 idx f*256 + lane*4 + q           [0,12288)
// layer2 (w2 [128][128]): f = tt*4+s, base 12288                           [12288,20480)
// proj   (wn2g [64][128]): f = tt*4+s (tt<4), base 20480                   [20480,24576)
__global__ void pack_nw(const float* __restrict__ w1, const float* __restrict__ w2,
                        const float* __restrict__ wn2g, uint32_t* __restrict__ nwf)
{
  int t = blockIdx.x * 256 + threadIdx.x;
  int q = t & 3, lane = (t >> 2) & 63;
  int vl = lane & 15, g = lane >> 4;
  if (t < 12288) {
    int f = t >> 8, s = f % 6, tt = f / 6;
    int o = tt * 16 + vl, k = s * 32 + g * 8 + 2 * q;
    nwf[t] = pack_h2(w1[o * K1 + k], w1[o * K1 + k + 1]);
  } else if (t < 20480) {
    int f = (t - 12288) >> 8, s = f & 3, tt = f >> 2;
    int o = tt * 16 + vl, k = s * 32 + g * 8 + 2 * q;
    nwf[t] = pack_h2(w2[o * 128 + k], w2[o * 128 + k + 1]);
  } else if (t < 24576) {
    int f = (t - 20480) >> 8, s = f & 3, tt = f >> 2;
    int o = tt * 16 + vl, k = s * 32 + g * 8 + 2 * q;
    nwf[t] = pack_h2(wn2g[o * 128 + k], wn2g[o * 128 + k + 1]);
  }
}

// ---------------- pack wc1/wc2 into MFMA A-fragments (voxel) ----------------
__global__ void pack_wc(const float* __restrict__ wc1, const float* __restrict__ wc2,
                        uint32_t* __restrict__ wf)
{
  int t = blockIdx.x * 256 + threadIdx.x;
  if (t < 4096) {
    int q = t & 3, lane = (t >> 2) & 63, f = t >> 8;
    int s = f & 3, tt = f >> 2;
    int o = tt * 16 + (lane & 15);
    int k = s * 32 + (lane >> 4) * 8 + 2 * q;
    wf[t] = pack_h2(wc1[o * 128 + k], wc1[o * 128 + k + 1]);
  } else if (t < 6144) {
    int u = t - 4096;
    int q = u & 3, lane = (u >> 2) & 63, f = u >> 8;
    int s = f & 1, tt = f >> 1;
    int o = tt * 16 + (lane & 15);
    int k = s * 32 + (lane >> 4) * 8 + 2 * q;
    wf[t] = pack_h2(wc2[o * 64 + k], wc2[o * 64 + k + 1]);
  }
}

// ---------------- transpose grid -> channel-last fp16 pairs ----------------
__global__ void transpose_kernel(const float* __restrict__ grid, uint32_t* __restrict__ gt)
{
  __shared__ float tile[64][65];
  int bx = blockIdx.x;                  // 0..16383
  int b = bx >> 12;
  int dhw0 = (bx & 4095) << 6;
  const float* gbase = grid + ((size_t)b * 64) * DHW + dhw0;
  int c0 = threadIdx.x >> 6, d = threadIdx.x & 63;
  #pragma unroll
  for (int i = 0; i < 16; ++i)
    tile[i * 4 + c0][d] = gbase[(size_t)(i * 4 + c0) * DHW + d];
  __syncthreads();
  uint32_t* tb = gt + ((size_t)b * DHW + dhw0) * 32;
  int p = threadIdx.x & 31, r0 = threadIdx.x >> 5;
  #pragma unroll
  for (int i = 0; i < 8; ++i) {
    int dd = i * 8 + r0;
    tb[(size_t)dd * 32 + p] = pack_h2(tile[2 * p][dd], tile[2 * p + 1][dd]);
  }
}

// ---------------- gather: corners + trilinear sample + z pack ----------------
__launch_bounds__(256)
__global__ void gather_kernel(const float* __restrict__ h, const float* __restrict__ x,
                              const uint32_t* __restrict__ gridT, const int* __restrict__ nbat,
                              const float* __restrict__ cmin, const float* __restrict__ sstr,
                              uint32_t* __restrict__ zg, int* __restrict__ cfg,
                              float* __restrict__ cwg)
{
  const int l = threadIdx.x & 63;
  const int w = threadIdx.x >> 6;
  const int gw = blockIdx.x * 4 + w;
  const int nw = gridDim.x * 4;
  const int p = l & 31, kb = l >> 5;
  const float c0 = cmin[0], c1 = cmin[1], c2 = cmin[2];
  const float st0 = sstr[0], st1 = sstr[1], st2 = sstr[2];

  for (int idx = gw; idx < NNODES / 2; idx += nw) {
    #pragma unroll
    for (int nd = 0; nd < 2; ++nd) {
      int n = 2 * idx + nd;
      float gx = (x[n * 3 + 0] - c0) / st0;
      float gy = (x[n * 3 + 1] - c1) / st1;
      float gz = (x[n * 3 + 2] - c2) / st2;
      float fx0 = floorf(gx), fy0 = floorf(gy), fz0 = floorf(gz);
      float fx = fminf(fmaxf(gx - fx0, 0.f), 1.f);
      float fy = fminf(fmaxf(gy - fy0, 0.f), 1.f);
      float fz = fminf(fmaxf(gz - fz0, 0.f), 1.f);
      int ix0 = (int)fx0, iy0 = (int)fy0, iz0 = (int)fz0;
      int b = nbat[n];

      float cw[8]; int cf[8];
      #pragma unroll
      for (int k = 0; k < 8; ++k) {
        int xi = (k & 1) ? ix0 + 1 : ix0;
        int yi = (k & 2) ? iy0 + 1 : iy0;
        int zi = (k & 4) ? iz0 + 1 : iz0;
        float wx = (k & 1) ? fx : 1.f - fx;
        float wy = (k & 2) ? fy : 1.f - fy;
        float wz = (k & 4) ? fz : 1.f - fz;
        bool valid = (xi >= 0) & (xi < 64) & (yi >= 0) & (yi < 64) & (zi >= 0) & (zi < 64);
        int xc = min(max(xi, 0), 63), yc = min(max(yi, 0), 63), zc = min(max(zi, 0), 63);
        cw[k] = valid ? wx * wy * wz : 0.f;
        cf[k] = b * DHW + ((zc << 12) | (yc << 6) | xc);
      }

      float slo = 0.f, shi = 0.f;
      #pragma unroll
      for (int j = 0; j < 4; ++j) {
        int k = 2 * j + kb;
        h2 gv = as_h2(gridT[(size_t)cf[k] * 32 + p]);
        slo = fmaf(cw[k], (float)gv.x, slo);
        shi = fmaf(cw[k], (float)gv.y, shi);
      }
      slo += __shfl_xor(slo, 32);
      shi += __shfl_xor(shi, 32);

      float2 hv = *(const float2*)&h[(size_t)n * NCH + 2 * l];
      zg[(size_t)n * 96 + l] = pack_h2(hv.x, hv.y);
      if (l < 32) zg[(size_t)n * 96 + 64 + p] = pack_h2(slo, shi);
      if (l == 0) {
        int4* cfp = (int4*)&cfg[n * 8];
        cfp[0] = make_int4(cf[0], cf[1], cf[2], cf[3]);
        cfp[1] = make_int4(cf[4], cf[5], cf[6], cf[7]);
        float4* cwp = (float4*)&cwg[n * 8];
        cwp[0] = make_float4(cw[0], cw[1], cw[2], cw[3]);
        cwp[1] = make_float4(cw[4], cw[5], cw[6], cw[7]);
      }
    }
  }
}

// ---------------- node MLP (MFMA): 64 nodes/block, wave w owns out-ch 32w..32w+31 ----
__launch_bounds__(256, 2)
__global__ void nodemlp_kernel(const uint32_t* __restrict__ zg, const uint32_t* __restrict__ nwf,
                               const float* __restrict__ b1, const float* __restrict__ b2,
                               const float* __restrict__ ln_g, const float* __restrict__ ln_b,
                               const float* __restrict__ bn2g,
                               float* __restrict__ hn_out, uint32_t* __restrict__ prjv)
{
  __shared__ __align__(16) uint32_t g1z[64][68];
  __shared__ float wpart[4][64][2];

  const int lane = threadIdx.x & 63, w = threadIdx.x >> 6;
  const int g = lane >> 4, vl = lane & 15;
  const int n0 = blockIdx.x * 64;

  const uint4* nf4 = (const uint4*)nwf;
  uint4 a1f[2][6], a2f[2][4], apf[4];
  #pragma unroll
  for (int j = 0; j < 2; ++j) {
    int tt = 2 * w + j;
    #pragma unroll
    for (int s = 0; s < 6; ++s) a1f[j][s] = nf4[(tt * 6 + s) * 64 + lane];
    #pragma unroll
    for (int s = 0; s < 4; ++s) a2f[j][s] = nf4[3072 + (tt * 4 + s) * 64 + lane];
  }
  #pragma unroll
  for (int s = 0; s < 4; ++s) apf[s] = nf4[5120 + (w * 4 + s) * 64 + lane];

  float4 b1r[2], b2r[2], lgr[2], lbr[2], bnr;
  #pragma unroll
  for (int j = 0; j < 2; ++j) {
    int c = (2 * w + j) * 16 + g * 4;
    b1r[j] = *(const float4*)&b1[c];
    b2r[j] = *(const float4*)&b2[c];
    lgr[j] = *(const float4*)&ln_g[c];
    lbr[j] = *(const float4*)&ln_b[c];
  }
  bnr = *(const float4*)&bn2g[w * 16 + g * 4];

  // ---- layer1: z(192) -> silu -> g1z ----
  #pragma unroll
  for (int nc = 0; nc < 4; ++nc) {
    const uint32_t* zrow = zg + (size_t)(n0 + nc * 16 + vl) * 96;
    uint4 bfr[6];
    #pragma unroll
    for (int s = 0; s < 6; ++s) bfr[s] = *(const uint4*)&zrow[s * 16 + g * 4];
    f32x4 acc[2];
    acc[0][0]=b1r[0].x; acc[0][1]=b1r[0].y; acc[0][2]=b1r[0].z; acc[0][3]=b1r[0].w;
    acc[1][0]=b1r[1].x; acc[1][1]=b1r[1].y; acc[1][2]=b1r[1].z; acc[1][3]=b1r[1].w;
    #pragma unroll
    for (int s = 0; s < 6; ++s) {
      acc[0] = mfma16(a1f[0][s], bfr[s], acc[0]);
      acc[1] = mfma16(a1f[1][s], bfr[s], acc[1]);
    }
    #pragma unroll
    for (int j = 0; j < 2; ++j) {
      uint2 pr;
      pr.x = pack_h2(siluf(acc[j][0]), siluf(acc[j][1]));
      pr.y = pack_h2(siluf(acc[j][2]), siluf(acc[j][3]));
      *(uint2*)&g1z[nc * 16 + vl][(2 * w + j) * 8 + g * 2] = pr;
    }
  }
  __syncthreads();

  // ---- layer2 + residual + LN partials ----
  float hnv[2][4][4];
  #pragma unroll
  for (int nc = 0; nc < 4; ++nc) {
    uint4 bfr[4];
    #pragma unroll
    for (int s = 0; s < 4; ++s) bfr[s] = *(const uint4*)&g1z[nc * 16 + vl][s * 16 + g * 4];
    f32x4 acc[2];
    acc[0][0]=b2r[0].x; acc[0][1]=b2r[0].y; acc[0][2]=b2r[0].z; acc[0][3]=b2r[0].w;
    acc[1][0]=b2r[1].x; acc[1][1]=b2r[1].y; acc[1][2]=b2r[1].z; acc[1][3]=b2r[1].w;
    #pragma unroll
    for (int s = 0; s < 4; ++s) {
      acc[0] = mfma16(a2f[0][s], bfr[s], acc[0]);
      acc[1] = mfma16(a2f[1][s], bfr[s], acc[1]);
    }
    float s_ = 0.f, q_ = 0.f;
    #pragma unroll
    for (int j = 0; j < 2; ++j) {
      uint2 hp = *(const uint2*)&zg[(size_t)(n0 + nc * 16 + vl) * 96 + (2 * w + j) * 8 + g * 2];
      h2 p0 = as_h2(hp.x), p1 = as_h2(hp.y);
      float v0 = acc[j][0] + (float)p0.x;
      float v1 = acc[j][1] + (float)p0.y;
      float v2 = acc[j][2] + (float)p1.x;
      float v3 = acc[j][3] + (float)p1.y;
      hnv[j][nc][0] = v0; hnv[j][nc][1] = v1; hnv[j][nc][2] = v2; hnv[j][nc][3] = v3;
      s_ += v0 + v1 + v2 + v3;
      q_ += v0 * v0 + v1 * v1 + v2 * v2 + v3 * v3;
    }
    s_ += __shfl_xor(s_, 16); q_ += __shfl_xor(q_, 16);
    s_ += __shfl_xor(s_, 32); q_ += __shfl_xor(q_, 32);
    if (lane < 16) { wpart[w][nc * 16 + lane][0] = s_; wpart[w][nc * 16 + lane][1] = q_; }
  }
  __syncthreads();

  // ---- LN finalize + hn write + pz pack (overwrite g1z) ----
  #pragma unroll
  for (int nc = 0; nc < 4; ++nc) {
    int node = nc * 16 + vl;
    float2 p0 = *(const float2*)&wpart[0][node][0];
    float2 p1 = *(const float2*)&wpart[1][node][0];
    float2 p2 = *(const float2*)&wpart[2][node][0];
    float2 p3 = *(const float2*)&wpart[3][node][0];
    float mu = (p0.x + p1.x + p2.x + p3.x) * (1.f / 128.f);
    float var = (p0.y + p1.y + p2.y + p3.y) * (1.f / 128.f) - mu * mu;
    float rstd = rsqrtf(var + 1e-5f);
    #pragma unroll
    for (int j = 0; j < 2; ++j) {
      float y0 = (hnv[j][nc][0] - mu) * rstd * ((const float*)&lgr[j])[0] + ((const float*)&lbr[j])[0];
      float y1 = (hnv[j][nc][1] - mu) * rstd * ((const float*)&lgr[j])[1] + ((const float*)&lbr[j])[1];
      float y2 = (hnv[j][nc][2] - mu) * rstd * ((const float*)&lgr[j])[2] + ((const float*)&lbr[j])[2];
      float y3 = (hnv[j][nc][3] - mu) * rstd * ((const float*)&lgr[j])[3] + ((const float*)&lbr[j])[3];
      *(float4*)&hn_out[(size_t)(n0 + node) * NCH + (2 * w + j) * 16 + g * 4] =
          make_float4(y0, y1, y2, y3);
      uint2 pz;
      pz.x = pack_h2(y0, y1);
      pz.y = pack_h2(y2, y3);
      *(uint2*)&g1z[node][(2 * w + j) * 8 + g * 2] = pz;
    }
  }
  __syncthreads();

  // ---- proj: 128 -> 64, write fp16 pairs ----
  #pragma unroll
  for (int nc = 0; nc < 4; ++nc) {
    int node = nc * 16 + vl;
    uint4 bfr[4];
    #pragma unroll
    for (int s = 0; s < 4; ++s) bfr[s] = *(const uint4*)&g1z[node][s * 16 + g * 4];
    f32x4 acc;
    acc[0]=bnr.x; acc[1]=bnr.y; acc[2]=bnr.z; acc[3]=bnr.w;
    #pragma unroll
    for (int s = 0; s < 4; ++s) acc = mfma16(apf[s], bfr[s], acc);
    uint2 pr;
    pr.x = pack_h2(acc[0], acc[1]);
    pr.y = pack_h2(acc[2], acc[3]);
    *(uint2*)&prjv[(size_t)(n0 + node) * 32 + w * 8 + g * 2] = pr;
  }
}

// ---------------- scatter: fp16x2 atomics into volh ----------------
__launch_bounds__(256)
__global__ void scatter_kernel(const int* __restrict__ cfg, const float* __restrict__ cwg,
                               const uint32_t* __restrict__ prjv, uint32_t* __restrict__ volh)
{
  const int lane = threadIdx.x & 63;
  const int half = lane >> 5, c = lane & 31;
  const int wid = (blockIdx.x * 256 + threadIdx.x) >> 6;
  const int nw = (gridDim.x * 256) >> 6;
  const int total = NNODES * 8 / 2;
  for (int it = wid; it < total; it += nw) {
    int pr = it * 2 + half;
    int node = pr >> 3, k = pr & 7;
    float wv = cwg[node * 8 + k];
    if (wv != 0.f) {
      int gidx = cfg[node * 8 + k];
      h2 p = as_h2(prjv[(size_t)node * 32 + c]);
      uint32_t v = pack_h2(wv * (float)p.x, wv * (float)p.y);
      atomic_pk_add_f16(&volh[(size_t)gidx * 32 + c], v);
    }
  }
}

// ---------------- per-voxel MLP kernel (MFMA) ----------------
__launch_bounds__(256, 2)
__global__ void voxel_kernel(const float* __restrict__ grid, const uint32_t* __restrict__ volh,
                             const uint32_t* __restrict__ wf, const float* __restrict__ bc1,
                             const float* __restrict__ bc2,
                             _Float16* __restrict__ grh, float* __restrict__ partials)
{
  __shared__ __align__(16) uint32_t xt[64][68];
  __shared__ __align__(16) uint32_t g1b[4][16][36];
  __shared__ float part_s[4][128];

  const int tid = threadIdx.x;
  const int lane = tid & 63, wv = tid >> 6;
  const int g = lane >> 4, vl = lane & 15;
  const int b = blockIdx.x >> 12;
  const int dhw0 = (blockIdx.x & 4095) << 6;
  const float* gb = grid + (size_t)(b * 64) * DHW + dhw0;

  // stage grid half
  {
    int c2 = tid >> 3, vq = tid & 7;
    const float* p0 = gb + (size_t)(2 * c2) * DHW + 8 * vq;
    const float* p1 = gb + (size_t)(2 * c2 + 1) * DHW + 8 * vq;
    float4 a0 = *(const float4*)p0;
    float4 b0 = *(const float4*)(p0 + 4);
    float4 a1 = *(const float4*)p1;
    float4 b1 = *(const float4*)(p1 + 4);
    int v0 = 8 * vq;
    xt[v0 + 0][c2] = pack_h2(a0.x, a1.x);
    xt[v0 + 1][c2] = pack_h2(a0.y, a1.y);
    xt[v0 + 2][c2] = pack_h2(a0.z, a1.z);
    xt[v0 + 3][c2] = pack_h2(a0.w, a1.w);
    xt[v0 + 4][c2] = pack_h2(b0.x, b1.x);
    xt[v0 + 5][c2] = pack_h2(b0.y, b1.y);
    xt[v0 + 6][c2] = pack_h2(b0.z, b1.z);
    xt[v0 + 7][c2] = pack_h2(b0.w, b1.w);
  }
  // stage vol half (already fp16 pairs)
  {
    const uint32_t* vb = volh + ((size_t)b * DHW + dhw0) * 32;
    #pragma unroll
    for (int it = 0; it < 2; ++it) {
      int u = it * 256 + tid;
      int v = u >> 3, p4 = u & 7;
      *(uint4*)&xt[v][32 + 4 * p4] = *(const uint4*)&vb[(size_t)v * 32 + 4 * p4];
    }
  }

  const uint4* wf4 = (const uint4*)wf;
  uint4 w1f[4][4], w2f[4][2];
  #pragma unroll
  for (int t = 0; t < 4; ++t)
    #pragma unroll
    for (int s = 0; s < 4; ++s)
      w1f[t][s] = wf4[(t * 4 + s) * 64 + lane];
  #pragma unroll
  for (int t = 0; t < 4; ++t)
    #pragma unroll
    for (int s = 0; s < 2; ++s)
      w2f[t][s] = wf4[1024 + (t * 2 + s) * 64 + lane];

  f32x4 acc1[4];
  #pragma unroll
  for (int t = 0; t < 4; ++t) {
    #pragma unroll
    for (int r = 0; r < 4; ++r) acc1[t][r] = bc1[t * 16 + g * 4 + r];
  }

  __syncthreads();

  const int v = wv * 16 + vl;
  #pragma unroll
  for (int s = 0; s < 4; ++s) {
    uint4 xb = *(const uint4*)&xt[v][s * 16 + g * 4];
    #pragma unroll
    for (int t = 0; t < 4; ++t) acc1[t] = mfma16(w1f[t][s], xb, acc1[t]);
  }

  #pragma unroll
  for (int t = 0; t < 4; ++t) {
    uint2 pr;
    pr.x = pack_h2(siluf(acc1[t][0]), siluf(acc1[t][1]));
    pr.y = pack_h2(siluf(acc1[t][2]), siluf(acc1[t][3]));
    *(uint2*)&g1b[wv][vl][t * 8 + g * 2] = pr;
  }
  asm volatile("s_waitcnt lgkmcnt(0)" ::: "memory");

  f32x4 acc2[4];
  #pragma unroll
  for (int t = 0; t < 4; ++t) {
    #pragma unroll
    for (int r = 0; r < 4; ++r) acc2[t][r] = bc2[t * 16 + g * 4 + r];
  }
  #pragma unroll
  for (int s = 0; s < 2; ++s) {
    uint4 gv = *(const uint4*)&g1b[wv][vl][s * 16 + g * 4];
    #pragma unroll
    for (int t = 0; t < 4; ++t) acc2[t] = mfma16(w2f[t][s], gv, acc2[t]);
  }

  // residual from staged fp16 grid + store fp16 + per-block stats
  const int dhw = dhw0 + v;
  #pragma unroll
  for (int t = 0; t < 4; ++t) {
    uint2 gp = *(const uint2*)&xt[v][t * 8 + g * 2];
    h2 g0 = as_h2(gp.x), g1 = as_h2(gp.y);
    float gc[4] = {(float)g0.x, (float)g0.y, (float)g1.x, (float)g1.y};
    #pragma unroll
    for (int r = 0; r < 4; ++r) {
      int o = t * 16 + g * 4 + r;
      float grv = gc[r] + acc2[t][r];
      grh[(size_t)(b * 64 + o) * DHW + dhw] = (_Float16)grv;
      float sv = grv, qv = grv * grv;
      sv += __shfl_xor(sv, 1, 64); qv += __shfl_xor(qv, 1, 64);
      sv += __shfl_xor(sv, 2, 64); qv += __shfl_xor(qv, 2, 64);
      sv += __shfl_xor(sv, 4, 64); qv += __shfl_xor(qv, 4, 64);
      sv += __shfl_xor(sv, 8, 64); qv += __shfl_xor(qv, 8, 64);
      if (vl == 0) { part_s[wv][2 * o] = sv; part_s[wv][2 * o + 1] = qv; }
    }
  }
  __syncthreads();
  if (tid < 128)
    partials[(size_t)blockIdx.x * 128 + tid] =
        part_s[0][tid] + part_s[1][tid] + part_s[2][tid] + part_s[3][tid];
}

// ---------------- reduce partials -> per (b,c) scale/shift ----------------
__global__ void stats_kernel(const float* __restrict__ partials, const float* __restrict__ in_g,
                             const float* __restrict__ in_b, float* __restrict__ stats)
{
  int bo = blockIdx.x;
  int b = bo >> 6, o = bo & 63;
  float s = 0.f, q = 0.f;
  for (int k = threadIdx.x; k < 4096; k += 256) {
    const float* pp = partials + (size_t)(b * 4096 + k) * 128 + 2 * o;
    s += pp[0]; q += pp[1];
  }
  __shared__ float sred[256], qred[256];
  sred[threadIdx.x] = s; qred[threadIdx.x] = q;
  __syncthreads();
  for (int st = 128; st >= 1; st >>= 1) {
    if (threadIdx.x < st) { sred[threadIdx.x] += sred[threadIdx.x + st]; qred[threadIdx.x] += qred[threadIdx.x + st]; }
    __syncthreads();
  }
  if (threadIdx.x == 0) {
    float mu = sred[0] * (1.f / (float)DHW);
    float var = qred[0] * (1.f / (float)DHW) - mu * mu;
    float rstd = rsqrtf(var + 1e-5f);
    float scale = rstd * in_g[o];
    stats[2 * bo] = scale;
    stats[2 * bo + 1] = in_b[o] - mu * scale;
  }
}

// ---------------- apply instance norm: grh (fp16) -> gr_out (f32) ----------------
__global__ void norm_kernel(const uint32_t* __restrict__ grh, const float* __restrict__ stats,
                            float* __restrict__ gr)
{
  const size_t total = (size_t)NBATCH * 64 * DHW / 2;   // u32 count
  size_t stride = (size_t)gridDim.x * 256;
  for (size_t i = blockIdx.x * 256 + threadIdx.x; i < total; i += stride) {
    int bo = (int)(i >> 17);
    float scale = stats[2 * bo], shift = stats[2 * bo + 1];
    h2 p = as_h2(grh[i]);
    float2 o;
    o.x = fmaf((float)p.x, scale, shift);
    o.y = fmaf((float)p.y, scale, shift);
    *(float2*)&gr[2 * i] = o;
  }
}

extern "C" void kernel_launch(void* const* d_in, const int* in_sizes, int n_in,
                              void* d_out, int out_size, void* d_ws, size_t ws_size,
                              hipStream_t stream)
{
  const float* h     = (const float*)d_in[0];
  const float* x     = (const float*)d_in[1];
  const float* grid  = (const float*)d_in[2];
  const int*   nbat  = (const int*)d_in[3];
  const float* cmin  = (const float*)d_in[4];
  const float* sstr  = (const float*)d_in[5];
  const float* w1    = (const float*)d_in[6];
  const float* b1    = (const float*)d_in[7];
  const float* w2    = (const float*)d_in[8];
  const float* b2    = (const float*)d_in[9];
  const float* ln_g  = (const float*)d_in[10];
  const float* ln_b  = (const float*)d_in[11];
  const float* wn2g  = (const float*)d_in[12];
  const float* bn2g  = (const float*)d_in[13];
  const float* wc1   = (const float*)d_in[14];
  const float* bc1   = (const float*)d_in[15];
  const float* wc2   = (const float*)d_in[16];
  const float* bc2   = (const float*)d_in[17];
  const float* in_g  = (const float*)d_in[18];
  const float* in_b  = (const float*)d_in[19];

  float* hn_out = (float*)d_out;
  float* gr_out = (float*)d_out + (size_t)NNODES * NCH;

  char* ws = (char*)d_ws;
  uint32_t* volh     = (uint32_t*)(ws + VOLH_OFF);     // 134MB fp16 pairs
  float*    partials = (float*)(ws + PART_OFF);
  float*    stats    = (float*)(ws + STAT_OFF);
  uint32_t* nwf      = (uint32_t*)(ws + NWF_OFF);
  uint32_t* wf       = (uint32_t*)(ws + WF_OFF);
  uint32_t* prjv     = (uint32_t*)(ws + PRJ_OFF);
  int*      cfg      = (int*)(ws + CFG_OFF);
  float*    cwg      = (float*)(ws + CWG_OFF);
  uint32_t* zg       = (uint32_t*)(ws + ZG_OFF);
  uint32_t* gridT    = (uint32_t*)(ws + GT_OFF);       // overlaid by grh after gather
  _Float16* grh      = (_Float16*)(ws + GT_OFF);

  (void)hipMemsetAsync(volh, 0, VOLH_BYTES, stream);
  pack_nw<<<96, 256, 0, stream>>>(w1, w2, wn2g, nwf);
  pack_wc<<<24, 256, 0, stream>>>(wc1, wc2, wf);
  transpose_kernel<<<16384, 256, 0, stream>>>(grid, gridT);
  gather_kernel<<<1024, 256, 0, stream>>>(h, x, gridT, nbat, cmin, sstr, zg, cfg, cwg);
  nodemlp_kernel<<<3125, 256, 0, stream>>>(zg, nwf, b1, b2, ln_g, ln_b, bn2g, hn_out, prjv);
  scatter_kernel<<<2048, 256, 0, stream>>>(cfg, cwg, prjv, volh);
  voxel_kernel<<<16384, 256, 0, stream>>>(grid, volh, wf, bc1, bc2, grh, partials);
  stats_kernel<<<256, 256, 0, stream>>>(partials, in_g, in_b, stats);
  norm_kernel<<<8192, 256, 0, stream>>>((const uint32_t*)grh, stats, gr_out);
}